// Round 10
// baseline (87.505 us; speedup 1.0000x reference)
//
#include <hip/hip_runtime.h>
#include <hip/hip_bf16.h>

#define B_ 8
#define N_ 4096
#define M_ 4096
#define D_ 64
#define BNT (B_ * N_)   // 32768
#define BMT (B_ * M_)   // 32768
#define TA 64           // A band rows per block (fragments in registers)
#define TB 128          // B tile rows (LDS, double-buffered)
#define NT 256          // threads per block (4 waves)
#define CHUNK_TILES 8   // B tiles per block
#define CHUNK_B (TB * CHUNK_TILES)        // 1024
#define MCHUNK (M_ / CHUNK_B)             // 4
#define NBLK (N_ / TA * MCHUNK * B_)      // 2048 blocks, launched 1D

typedef short bf16x8 __attribute__((ext_vector_type(8)));
typedef float f32x4 __attribute__((ext_vector_type(4)));

__device__ __forceinline__ unsigned short f2bf(float f) {
  __hip_bfloat16 h = __float2bfloat16(f);
  return *reinterpret_cast<unsigned short*>(&h);
}

// Order-preserving float -> uint key for atomicMin/atomicMax(unsigned).
__device__ __forceinline__ unsigned fkey(float f) {
  unsigned b = __float_as_uint(f);
  return b ^ ((unsigned)((int)b >> 31) | 0x80000000u);
}
__device__ __forceinline__ float funkey(unsigned k) {
  unsigned b = (k & 0x80000000u) ? (k ^ 0x80000000u) : ~k;
  return __uint_as_float(b);
}

__device__ __forceinline__ bf16x8 cvt8(float4 lo, float4 hi) {
  union { unsigned short u[8]; bf16x8 v; } r;
  r.u[0] = f2bf(lo.x); r.u[1] = f2bf(lo.y); r.u[2] = f2bf(lo.z); r.u[3] = f2bf(lo.w);
  r.u[4] = f2bf(hi.x); r.u[5] = f2bf(hi.y); r.u[6] = f2bf(hi.z); r.u[7] = f2bf(hi.w);
  return r.v;
}

// Barrier that does NOT drain vmcnt: LDS coherence only. Our in-flight
// global loads target registers (per-wave private), so they may legally
// stay outstanding across the barrier — this is what __syncthreads forbids
// (compiler emits vmcnt(0) before s_barrier) and what capped R2-R8.
__device__ __forceinline__ void block_sync_lds() {
  asm volatile("s_waitcnt lgkmcnt(0)" ::: "memory");
  __builtin_amdgcn_s_barrier();
  __builtin_amdgcn_sched_barrier(0);
}

// Issue global loads for one 128x64 bf16 tile into 4 per-thread registers.
// Chunk q = i*NT + t covers tile bytes [q*16, q*16+16) (bf16) — coalesced.
template <bool BF>
__device__ __forceinline__ void stage_load(const char* gtile, bf16x8* arr, int t) {
#pragma unroll
  for (int i = 0; i < 4; i++) {
    int q = i * NT + t;
    if (BF) {
      arr[i] = *(const bf16x8*)(gtile + (size_t)q * 16);
    } else {
      const float4* p = (const float4*)(gtile + (size_t)q * 32);
      arr[i] = cvt8(p[0], p[1]);
    }
  }
}

// ds_write the staged registers into the XOR-swizzled LDS tile.
__device__ __forceinline__ void stage_write(unsigned short* lds, const bf16x8* arr, int t) {
#pragma unroll
  for (int i = 0; i < 4; i++) {
    int q = i * NT + t;
    int row = q >> 3, col = q & 7;
    int dst = (row * 128 + col * 16) ^ ((row & 7) << 4);
    *(bf16x8*)((char*)lds + dst) = arr[i];
  }
}

// Kernel 1: norms + min-array + gmax init (+ optional conversion).
// predbf gets -2*pred folded in (exact power-of-2 scale): the fused gram
// then directly produces y2 - 2<a,b> via MFMA C-injection.
template <bool CONV>
__global__ __launch_bounds__(256) void prep_kernel(
    const float* __restrict__ pred, const float* __restrict__ label,
    unsigned short* __restrict__ predbf, unsigned short* __restrict__ labelbf,
    float* __restrict__ x2, float* __restrict__ y2,
    unsigned* __restrict__ minN, unsigned* __restrict__ minM,
    unsigned* __restrict__ gmax) {
  int t = threadIdx.x;
  int lane = t & 15;
  long row = (long)blockIdx.x * 16 + (t >> 4);
  bool isA = row < BNT;
  const float4* src;
  unsigned short* bdst;
  float* ndst;
  unsigned* mdst;
  if (isA) {
    src = (const float4*)(pred + row * D_);
    bdst = predbf + row * D_;
    ndst = x2 + row;
    mdst = minN + row;
  } else {
    long r2 = row - BNT;
    src = (const float4*)(label + r2 * D_);
    bdst = labelbf + r2 * D_;
    ndst = y2 + r2;
    mdst = minM + r2;
  }
  float4 v = src[lane];
  if (CONV) {
    float s = isA ? -2.f : 1.f;
    ushort4 p;
    p.x = f2bf(s * v.x); p.y = f2bf(s * v.y);
    p.z = f2bf(s * v.z); p.w = f2bf(s * v.w);
    *(ushort4*)(bdst + lane * 4) = p;
  }
  float s = v.x * v.x + v.y * v.y + v.z * v.z + v.w * v.w;
  s += __shfl_xor(s, 1);
  s += __shfl_xor(s, 2);
  s += __shfl_xor(s, 4);
  s += __shfl_xor(s, 8);
  if (lane == 0) {
    *ndst = s;
    *mdst = 0xFFFFFFFFu;  // +inf key
  }
  if (blockIdx.x == 0 && t < 2) gmax[t] = 0u;
}

// Kernel 2: fused pass. 4 waves; A-band 64 rows in regs (all waves share);
// B-chunk streamed through 2 LDS tile buffers with REGISTER staging:
//   iter it: [issue loads tile it+2 -> stg] [compute on Bs[it&1]]
//            [ds_write stg(tile it+1) -> Bs[(it+1)&1]] [lgkm-only barrier]
// Loads stay in flight across barriers (~2 iters of cover); the barrier
// never exposes global latency. acc = splat(y2[m]) + (-2A)B via C-injection.
//   minN[n]: rmin regs -> shfl + cross-wave LDS -> atomic (end)
//   minM[m]: per-iter in-wave reduce -> cmSlab -> batch atomic flush (end)
template <bool BF>
__global__ __launch_bounds__(NT) void fused_kernel(
    const void* __restrict__ Asrc, const void* __restrict__ Bsrc,
    const float* __restrict__ x2g, const float* __restrict__ y2g,
    unsigned* __restrict__ minN, unsigned* __restrict__ minM) {
  __shared__ alignas(16) unsigned short Bs[2][TB * 64];
  __shared__ float y2l[CHUNK_B];
  __shared__ float cmSlab[CHUNK_B];
  __shared__ float red[4][TA];

  const int t = threadIdx.x;
  // XCD-aware decode (R8): batch k pinned to XCD k under round-robin.
  const int bid = blockIdx.x;
  const int b = bid & 7;
  const int j = bid >> 3;
  const int a0 = (j & 63) * TA;
  const int m0 = (j >> 6) * CHUNK_B;

  const int w = t >> 6, l = t & 63;
  const int g = l >> 4, c = l & 15;

  const size_t tilebytes = (size_t)TB * 64 * (BF ? 2 : 4);
  const char* Bgl = (const char*)Bsrc + ((size_t)b * M_ + m0) * (BF ? 128 : 256);

  // y2 chunk -> LDS (4KB, once)
  ((float4*)y2l)[t] = ((const float4*)(y2g + (size_t)b * M_ + m0))[t];

  // ---- pipeline prologue: tiles 0 and 1 in flight, tile 0 written ----
  bf16x8 stg[2][4];
  stage_load<BF>(Bgl, stg[0], t);
  stage_load<BF>(Bgl + tilebytes, stg[1], t);

  // A fragments (full 64-row band), direct global->reg (L2-hot, one-time)
  bf16x8 af[2][4];
  if (BF) {
    const unsigned short* Ab =
        (const unsigned short*)Asrc + ((size_t)b * N_ + a0) * D_;
#pragma unroll
    for (int kk = 0; kk < 2; kk++)
#pragma unroll
      for (int mi = 0; mi < 4; mi++)
        af[kk][mi] =
            *(const bf16x8*)(Ab + (size_t)(mi * 16 + c) * D_ + kk * 32 + g * 8);
  } else {
    const float* Af = (const float*)Asrc + ((size_t)b * N_ + a0) * D_;
#pragma unroll
    for (int kk = 0; kk < 2; kk++)
#pragma unroll
      for (int mi = 0; mi < 4; mi++) {
        const float4* p =
            (const float4*)(Af + (size_t)(mi * 16 + c) * D_ + kk * 32 + g * 8);
        float4 lo = p[0], hi = p[1];
        lo.x *= -2.f; lo.y *= -2.f; lo.z *= -2.f; lo.w *= -2.f;
        hi.x *= -2.f; hi.y *= -2.f; hi.z *= -2.f; hi.w *= -2.f;
        af[kk][mi] = cvt8(lo, hi);
      }
  }

  // x2 per output A-row (loop-invariant)
  float x2v[4][4];
#pragma unroll
  for (int mi = 0; mi < 4; mi++)
#pragma unroll
    for (int e = 0; e < 4; e++)
      x2v[mi][e] = x2g[(size_t)b * N_ + a0 + mi * 16 + g * 4 + e];

  float rmin[4][4];
#pragma unroll
  for (int mi = 0; mi < 4; mi++)
#pragma unroll
    for (int e = 0; e < 4; e++) rmin[mi][e] = INFINITY;

  stage_write(Bs[0], stg[0], t);  // waits vmcnt for tile0 regs only
  block_sync_lds();               // tile0 + y2l visible; tile1 still in flight

#pragma unroll
  for (int it = 0; it < CHUNK_TILES; ++it) {
    // issue loads for tile it+2 (lands ~2 iterations from now)
    if (it + 2 < CHUNK_TILES)
      stage_load<BF>(Bgl + (size_t)(it + 2) * tilebytes, stg[it & 1], t);

    const char* Bcur = (const char*)(&Bs[it & 1][0]);
#pragma unroll
    for (int h = 0; h < 2; ++h) {
      const int r = w * 32 + h * 16 + c;  // this wave's B row in tile
      const float nv = y2l[it * TB + r];
      bf16x8 b0 = *(const bf16x8*)(Bcur + ((r * 128 + g * 16) ^ ((r & 7) << 4)));
      bf16x8 b1 = *(const bf16x8*)(Bcur + ((r * 128 + 64 + g * 16) ^ ((r & 7) << 4)));

      f32x4 acc[4];
#pragma unroll
      for (int mi = 0; mi < 4; mi++) acc[mi] = (f32x4){nv, nv, nv, nv};
#pragma unroll
      for (int mi = 0; mi < 4; mi++)
        acc[mi] = __builtin_amdgcn_mfma_f32_16x16x32_bf16(af[0][mi], b0, acc[mi], 0, 0, 0);
#pragma unroll
      for (int mi = 0; mi < 4; mi++)
        acc[mi] = __builtin_amdgcn_mfma_f32_16x16x32_bf16(af[1][mi], b1, acc[mi], 0, 0, 0);

      // epilogue: v = y2 - 2ab; rmin=fmin(rmin,v); cm=min(v+x2)-y2
      float cs[4];
#pragma unroll
      for (int mi = 0; mi < 4; mi++) {
        float c0 = acc[mi][0] + x2v[mi][0];
        float c1 = acc[mi][1] + x2v[mi][1];
        float c2 = acc[mi][2] + x2v[mi][2];
        float c3 = acc[mi][3] + x2v[mi][3];
        cs[mi] = fminf(fminf(c0, c1), fminf(c2, c3));
#pragma unroll
        for (int e = 0; e < 4; e++)
          rmin[mi][e] = fminf(rmin[mi][e], acc[mi][e]);
      }
      float cm = fminf(fminf(cs[0], cs[1]), fminf(cs[2], cs[3]));
      cm = fminf(cm, __shfl_xor(cm, 16));
      cm = fminf(cm, __shfl_xor(cm, 32));
      if (g == 0) cmSlab[it * TB + r] = cm - nv;
    }

    // write tile it+1 into the other buffer; barrier (lgkm only)
    if (it + 1 < CHUNK_TILES) {
      stage_write(Bs[(it + 1) & 1], stg[(it + 1) & 1], t);
      block_sync_lds();
    }
  }

  // rmin finish: c-lane shfl reduce, cross-wave LDS combine, atomic per row
#pragma unroll
  for (int mi = 0; mi < 4; mi++)
#pragma unroll
    for (int e = 0; e < 4; e++) {
      float r = rmin[mi][e];
      r = fminf(r, __shfl_xor(r, 1));
      r = fminf(r, __shfl_xor(r, 2));
      r = fminf(r, __shfl_xor(r, 4));
      r = fminf(r, __shfl_xor(r, 8));
      rmin[mi][e] = r;
    }
  if (c == 0) {
#pragma unroll
    for (int mi = 0; mi < 4; mi++)
#pragma unroll
      for (int e = 0; e < 4; e++)
        red[w][mi * 16 + g * 4 + e] = rmin[mi][e];
  }
  __syncthreads();
  if (t < TA) {
    float m = fminf(fminf(red[0][t], red[1][t]), fminf(red[2][t], red[3][t]));
    atomicMin(&minN[(size_t)b * N_ + a0 + t], fkey(m));
  }
  // col-min flush: one atomic per B row of the chunk (4 per thread)
#pragma unroll
  for (int i = 0; i < CHUNK_B / NT; i++) {
    int r = i * NT + t;
    atomicMin(&minM[(size_t)b * M_ + m0 + r], fkey(cmSlab[r]));
  }
}

// Kernel 3a: per-slice max of (norm + min), atomicMax into gmax[dir].
__global__ __launch_bounds__(256) void final1_kernel(
    const unsigned* __restrict__ minN, const unsigned* __restrict__ minM,
    const float* __restrict__ x2, const float* __restrict__ y2,
    unsigned* __restrict__ gmax) {
  int dir = blockIdx.x >> 5;
  int blk = blockIdx.x & 31;
  const unsigned* src = dir ? minM : minN;
  const float* nrm = dir ? y2 : x2;
  size_t base = (size_t)blk * 256;  // in uint4/float4 units
  float mx = -INFINITY;
  {
    int i = threadIdx.x;
    uint4 k = ((const uint4*)src)[base + i];
    float4 nv = ((const float4*)nrm)[base + i];
    mx = fmaxf(mx, nv.x + funkey(k.x));
    mx = fmaxf(mx, nv.y + funkey(k.y));
    mx = fmaxf(mx, nv.z + funkey(k.z));
    mx = fmaxf(mx, nv.w + funkey(k.w));
  }
#pragma unroll
  for (int mask = 1; mask < 64; mask <<= 1) mx = fmaxf(mx, __shfl_xor(mx, mask));
  __shared__ float sm[4];
  if ((threadIdx.x & 63) == 0) sm[threadIdx.x >> 6] = mx;
  __syncthreads();
  if (threadIdx.x == 0) {
    mx = fmaxf(fmaxf(sm[0], sm[1]), fmaxf(sm[2], sm[3]));
    atomicMax(&gmax[dir], fkey(mx));
  }
}

__global__ void final2_kernel(const unsigned* __restrict__ gmax, float* __restrict__ out) {
  if (threadIdx.x == 0)
    out[0] = sqrtf(fmaxf(funkey(gmax[0]), 1e-12f)) +
             sqrtf(fmaxf(funkey(gmax[1]), 1e-12f));
}

extern "C" void kernel_launch(void* const* d_in, const int* in_sizes, int n_in,
                              void* d_out, int out_size, void* d_ws, size_t ws_size,
                              hipStream_t stream) {
  const float* pred = (const float*)d_in[0];
  const float* label = (const float*)d_in[1];
  char* ws = (char*)d_ws;

  const size_t bfBytes = (size_t)BNT * D_ * 2;  // 4 MB per array
  const size_t needFast = 2 * bfBytes + (size_t)(BNT + BMT) * 8 + 64;

  if (ws_size >= needFast) {
    unsigned short* predbf = (unsigned short*)ws;
    unsigned short* labelbf = (unsigned short*)(ws + bfBytes);
    float* x2 = (float*)(ws + 2 * bfBytes);
    float* y2 = x2 + BNT;
    unsigned* minN = (unsigned*)(y2 + BMT);
    unsigned* minM = minN + BNT;
    unsigned* gmax = minM + BMT;

    prep_kernel<true><<<(BNT + BMT) / 16, 256, 0, stream>>>(
        pred, label, predbf, labelbf, x2, y2, minN, minM, gmax);
    fused_kernel<true><<<NBLK, NT, 0, stream>>>(
        predbf, labelbf, x2, y2, minN, minM);
    final1_kernel<<<64, 256, 0, stream>>>(minN, minM, x2, y2, gmax);
    final2_kernel<<<1, 64, 0, stream>>>(gmax, (float*)d_out);
  } else {
    float* x2 = (float*)ws;
    float* y2 = x2 + BNT;
    unsigned* minN = (unsigned*)(y2 + BMT);
    unsigned* minM = minN + BNT;
    unsigned* gmax = minM + BMT;

    prep_kernel<false><<<(BNT + BMT) / 16, 256, 0, stream>>>(
        pred, label, nullptr, nullptr, x2, y2, minN, minM, gmax);
    fused_kernel<false><<<NBLK, NT, 0, stream>>>(
        pred, label, x2, y2, minN, minM);
    final1_kernel<<<64, 256, 0, stream>>>(minN, minM, x2, y2, gmax);
    final2_kernel<<<1, 64, 0, stream>>>(gmax, (float*)d_out);
  }
}